// Round 1
// baseline (2645.714 us; speedup 1.0000x reference)
//
#include <hip/hip_runtime.h>
#include <hip/hip_bf16.h>
#include <math.h>

#define NN 40000
#define EE 250000
#define HH 4
#define DD 64
#define HDIM 256

// ---------------- CSR build ----------------

__global__ void zero_kernel(int* p, int n) {
    int i = blockIdx.x * blockDim.x + threadIdx.x;
    if (i < n) p[i] = 0;
}

__global__ void count_kernel(const int* __restrict__ dst, int* __restrict__ deg, int n) {
    int i = blockIdx.x * blockDim.x + threadIdx.x;
    if (i < n) atomicAdd(&deg[dst[i]], 1);
}

// 3 blocks, one per edge type; Hillis-Steele scan over chunks of 1024 with carry.
__global__ __launch_bounds__(1024) void scan3_kernel(const int* d0, const int* d1, const int* d2,
                                                     int* r0, int* r1, int* r2, int n) {
    const int* deg = blockIdx.x == 0 ? d0 : (blockIdx.x == 1 ? d1 : d2);
    int* rowptr    = blockIdx.x == 0 ? r0 : (blockIdx.x == 1 ? r1 : r2);
    __shared__ int buf[1024];
    __shared__ int carry_s;
    int tid = threadIdx.x;
    if (tid == 0) { carry_s = 0; rowptr[0] = 0; }
    __syncthreads();
    for (int base = 0; base < n; base += 1024) {
        int i = base + tid;
        int v = (i < n) ? deg[i] : 0;
        buf[tid] = v;
        __syncthreads();
        for (int off = 1; off < 1024; off <<= 1) {
            int t = (tid >= off) ? buf[tid - off] : 0;
            __syncthreads();
            buf[tid] += t;
            __syncthreads();
        }
        int incl = buf[tid];
        int tot = buf[1023];
        if (i < n) rowptr[i + 1] = carry_s + incl;
        __syncthreads();
        if (tid == 0) carry_s += tot;
        __syncthreads();
    }
}

__global__ void scatter_kernel(const int* __restrict__ src, const int* __restrict__ dst,
                               const int* __restrict__ rowptr, int* __restrict__ cur,
                               int* __restrict__ colsrc, int n) {
    int i = blockIdx.x * blockDim.x + threadIdx.x;
    if (i < n) {
        int d = dst[i];
        int p = rowptr[d] + atomicAdd(&cur[d], 1);
        colsrc[p] = src[i];
    }
}

// ---------------- fp32 tiled GEMM: C[M,Nc] = A[M,K] @ B[K,Nc] (+bias) ----------------
// BM=BN=128, BK=8, 256 threads, 8x8 microtile per thread. Nc%128==0, K%8==0 required.

__global__ __launch_bounds__(256) void gemm_kernel(const float* __restrict__ A,
                                                   const float* __restrict__ B,
                                                   const float* __restrict__ bias,
                                                   float* __restrict__ C,
                                                   int M, int K, int Nc) {
    __shared__ float As[8][128];
    __shared__ float Bs[8][128];
    int tid = threadIdx.x;
    int m0 = blockIdx.x * 128;
    int n0 = blockIdx.y * 128;
    int tx = tid & 15, ty = tid >> 4;

    float acc[8][8];
#pragma unroll
    for (int i = 0; i < 8; i++)
#pragma unroll
        for (int j = 0; j < 8; j++) acc[i][j] = 0.f;

    int ar = tid >> 1;         // 0..127 (row within A tile)
    int ac = (tid & 1) * 4;    // 0 or 4 (col group within A tile)
    int bk = tid >> 5;         // 0..7   (row within B tile)
    int bn = (tid & 31) * 4;   // col within B tile
    int arow = m0 + ar; if (arow >= M) arow = M - 1;  // clamp; stores are guarded
    const float* Aptr = A + (size_t)arow * K + ac;
    const float* Bptr = B + (size_t)bk * Nc + n0 + bn;

    for (int k0 = 0; k0 < K; k0 += 8) {
        float4 av = *(const float4*)(Aptr + k0);
        float4 bv = *(const float4*)(Bptr + (size_t)k0 * Nc);
        __syncthreads();
        As[ac + 0][ar] = av.x; As[ac + 1][ar] = av.y;
        As[ac + 2][ar] = av.z; As[ac + 3][ar] = av.w;
        *(float4*)&Bs[bk][bn] = bv;
        __syncthreads();
#pragma unroll
        for (int kk = 0; kk < 8; kk++) {
            float a[8], b[8];
            *(float4*)(a)     = *(const float4*)&As[kk][ty * 8];
            *(float4*)(a + 4) = *(const float4*)&As[kk][ty * 8 + 4];
            *(float4*)(b)     = *(const float4*)&Bs[kk][tx * 8];
            *(float4*)(b + 4) = *(const float4*)&Bs[kk][tx * 8 + 4];
#pragma unroll
            for (int i = 0; i < 8; i++)
#pragma unroll
                for (int j = 0; j < 8; j++) acc[i][j] = fmaf(a[i], b[j], acc[i][j]);
        }
    }

#pragma unroll
    for (int i = 0; i < 8; i++) {
        int row = m0 + ty * 8 + i;
        if (row < M) {
            float* Cp = C + (size_t)row * Nc + n0 + tx * 8;
#pragma unroll
            for (int j = 0; j < 8; j++) {
                float v = acc[i][j];
                if (bias) v += bias[n0 + tx * 8 + j];
                Cp[j] = v;
            }
        }
    }
}

// ---------------- el/er: per (node, head) attention dot products ----------------

__global__ __launch_bounds__(256) void elr_kernel(const float* __restrict__ f,
                                                  const float* __restrict__ al,
                                                  const float* __restrict__ ar,
                                                  float* __restrict__ el, float* __restrict__ er) {
    int n = blockIdx.x;
    int h = threadIdx.x >> 6;   // wave = head
    int d = threadIdx.x & 63;
    float v = f[(size_t)n * HDIM + h * DD + d];
    float vl = v * al[h * DD + d];
    float vr = v * ar[h * DD + d];
#pragma unroll
    for (int off = 32; off; off >>= 1) {
        vl += __shfl_down(vl, off);
        vr += __shfl_down(vr, off);
    }
    if (d == 0) {
        el[n * HH + h] = vl;
        er[n * HH + h] = vr;
    }
}

// ---------------- per-dst online-softmax aggregation over CSR ----------------
// One block per dst node; wave w = head w; lane = channel d.

__global__ __launch_bounds__(256) void aggregate_kernel(const int* __restrict__ rowptr,
                                                        const int* __restrict__ colsrc,
                                                        const float* __restrict__ f,
                                                        const float* __restrict__ el,
                                                        const float* __restrict__ er,
                                                        const float* __restrict__ bias,
                                                        float* __restrict__ out, int accumulate) {
    int n = blockIdx.x;
    int h = threadIdx.x >> 6;
    int d = threadIdx.x & 63;
    int beg = rowptr[n], end = rowptr[n + 1];
    float ern = er[n * HH + h];
    float m = -INFINITY, s = 0.f, acc = 0.f;
    for (int p = beg; p < end; p++) {
        int srcn = colsrc[p];
        float e = el[srcn * HH + h] + ern;
        e = (e > 0.f) ? e : 0.2f * e;          // leaky_relu slope 0.2
        float mn = fmaxf(m, e);
        float scale = __expf(m - mn);           // exp(-inf)=0 on first edge
        float w = __expf(e - mn);
        s = s * scale + w;
        acc = acc * scale + w * f[(size_t)srcn * HDIM + h * DD + d];
        m = mn;
    }
    float res = (s > 0.f) ? acc / s : 0.f;
    res += bias[h * DD + d];
    size_t oi = (size_t)n * HDIM + h * DD + d;
    if (accumulate) out[oi] += res;
    else out[oi] = res;
}

__global__ void leaky_kernel(float* __restrict__ p, int n) {
    int i = blockIdx.x * blockDim.x + threadIdx.x;
    if (i < n) {
        float v = p[i];
        p[i] = (v >= 0.f) ? v : 0.01f * v;     // F.leaky_relu default slope
    }
}

// ---------------- launch ----------------

extern "C" void kernel_launch(void* const* d_in, const int* in_sizes, int n_in,
                              void* d_out, int out_size, void* d_ws, size_t ws_size,
                              hipStream_t stream) {
    const float* x = (const float*)d_in[0];
    const int* src[3] = {(const int*)d_in[1], (const int*)d_in[3], (const int*)d_in[5]};
    const int* dst[3] = {(const int*)d_in[2], (const int*)d_in[4], (const int*)d_in[6]};
    const float *W[2][3], *AL[2][3], *AR[2][3], *BB[2][3];
    int idx = 7;
    for (int l = 0; l < 2; l++)
        for (int t = 0; t < 3; t++) {
            W[l][t]  = (const float*)d_in[idx++];
            AL[l][t] = (const float*)d_in[idx++];
            AR[l][t] = (const float*)d_in[idx++];
            BB[l][t] = (const float*)d_in[idx++];
        }
    const float* Wout = (const float*)d_in[31];
    const float* bout = (const float*)d_in[32];
    float* out = (float*)d_out;

    // workspace carve (all 16B-aligned by construction)
    float* f  = (float*)d_ws;
    float* h1 = f  + (size_t)NN * HDIM;
    float* h2 = h1 + (size_t)NN * HDIM;
    float* el = h2 + (size_t)NN * HDIM;
    float* er = el + (size_t)NN * HH;
    int* ibase = (int*)(er + (size_t)NN * HH);
    int *rowptr[3], *colsrc[3], *cursor[3];
    for (int t = 0; t < 3; t++) {
        rowptr[t] = ibase; ibase += NN + 1;
        colsrc[t] = ibase; ibase += EE;
        cursor[t] = ibase; ibase += NN;
    }

    // ---- CSR build (every call; ws is re-poisoned between calls) ----
    for (int t = 0; t < 3; t++) {
        zero_kernel<<<(NN + 255) / 256, 256, 0, stream>>>(cursor[t], NN);
        count_kernel<<<(EE + 255) / 256, 256, 0, stream>>>(dst[t], cursor[t], EE);
    }
    scan3_kernel<<<3, 1024, 0, stream>>>(cursor[0], cursor[1], cursor[2],
                                         rowptr[0], rowptr[1], rowptr[2], NN);
    for (int t = 0; t < 3; t++) {
        zero_kernel<<<(NN + 255) / 256, 256, 0, stream>>>(cursor[t], NN);
        scatter_kernel<<<(EE + 255) / 256, 256, 0, stream>>>(src[t], dst[t], rowptr[t],
                                                             cursor[t], colsrc[t], EE);
    }

    // ---- 2 GAT layers ----
    const float* hin = x;
    float* houts[2] = {h1, h2};
    int Ks[2] = {1024, HDIM};
    for (int l = 0; l < 2; l++) {
        for (int t = 0; t < 3; t++) {
            dim3 g((NN + 127) / 128, HDIM / 128);
            gemm_kernel<<<g, 256, 0, stream>>>(hin, W[l][t], nullptr, f, NN, Ks[l], HDIM);
            elr_kernel<<<NN, 256, 0, stream>>>(f, AL[l][t], AR[l][t], el, er);
            aggregate_kernel<<<NN, 256, 0, stream>>>(rowptr[t], colsrc[t], f, el, er,
                                                     BB[l][t], houts[l], t > 0);
        }
        if (l == 0)
            leaky_kernel<<<(NN * HDIM + 255) / 256, 256, 0, stream>>>(h1, NN * HDIM);
        hin = houts[l];
    }

    // ---- output projection ----
    dim3 g((NN + 127) / 128, 1024 / 128);
    gemm_kernel<<<g, 256, 0, stream>>>(h2, Wout, bout, out, NN, HDIM, 1024);
}

// Round 2
// 1398.336 us; speedup vs baseline: 1.8920x; 1.8920x over previous
//
#include <hip/hip_runtime.h>
#include <hip/hip_bf16.h>
#include <math.h>

#define NN 40000
#define EE 250000
#define HH 4
#define DD 64
#define HDIM 256

typedef __attribute__((ext_vector_type(8))) short short8;
typedef __attribute__((ext_vector_type(4))) float floatx4;

#define ASYNC16(G, L) __builtin_amdgcn_global_load_lds( \
    (const __attribute__((address_space(1))) void*)(G), \
    (__attribute__((address_space(3))) void*)(L), 16, 0, 0)

// ---------------- CSR build ----------------

__global__ void zero_kernel(int* p, int n) {
    int i = blockIdx.x * blockDim.x + threadIdx.x;
    if (i < n) p[i] = 0;
}

__global__ void count_kernel(const int* __restrict__ dst, int* __restrict__ deg, int n) {
    int i = blockIdx.x * blockDim.x + threadIdx.x;
    if (i < n) atomicAdd(&deg[dst[i]], 1);
}

__global__ __launch_bounds__(1024) void scan3_kernel(const int* d0, const int* d1, const int* d2,
                                                     int* r0, int* r1, int* r2, int n) {
    const int* deg = blockIdx.x == 0 ? d0 : (blockIdx.x == 1 ? d1 : d2);
    int* rowptr    = blockIdx.x == 0 ? r0 : (blockIdx.x == 1 ? r1 : r2);
    __shared__ int buf[1024];
    __shared__ int carry_s;
    int tid = threadIdx.x;
    if (tid == 0) { carry_s = 0; rowptr[0] = 0; }
    __syncthreads();
    for (int base = 0; base < n; base += 1024) {
        int i = base + tid;
        int v = (i < n) ? deg[i] : 0;
        buf[tid] = v;
        __syncthreads();
        for (int off = 1; off < 1024; off <<= 1) {
            int t = (tid >= off) ? buf[tid - off] : 0;
            __syncthreads();
            buf[tid] += t;
            __syncthreads();
        }
        int incl = buf[tid];
        int tot = buf[1023];
        if (i < n) rowptr[i + 1] = carry_s + incl;
        __syncthreads();
        if (tid == 0) carry_s += tot;
        __syncthreads();
    }
}

__global__ void scatter_kernel(const int* __restrict__ src, const int* __restrict__ dst,
                               const int* __restrict__ rowptr, int* __restrict__ cur,
                               int* __restrict__ colsrc, int n) {
    int i = blockIdx.x * blockDim.x + threadIdx.x;
    if (i < n) {
        int d = dst[i];
        int p = rowptr[d] + atomicAdd(&cur[d], 1);
        colsrc[p] = src[i];
    }
}

// ---------------- conversions / weight packing ----------------

__global__ void f2b_kernel(const float* __restrict__ in, __hip_bfloat16* __restrict__ o, int n) {
    int i = blockIdx.x * blockDim.x + threadIdx.x;
    if (i < n) o[i] = __float2bfloat16(in[i]);
}

__global__ void leakyb_kernel(const float* __restrict__ in, __hip_bfloat16* __restrict__ o,
                              float slope, int n) {
    int i = blockIdx.x * blockDim.x + threadIdx.x;
    if (i < n) {
        float v = in[i];
        v = (v >= 0.f) ? v : slope * v;
        o[i] = __float2bfloat16(v);
    }
}

// Wt[n][k] = bf16(W[k][n]);  W is K x Nc row-major.
__global__ void transb_kernel(const float* __restrict__ W, __hip_bfloat16* __restrict__ Wt,
                              int K, int Nc) {
    int i = blockIdx.x * blockDim.x + threadIdx.x;
    if (i < K * Nc) {
        int k = i / Nc, n2 = i % Nc;
        Wt[(size_t)n2 * K + k] = __float2bfloat16(W[i]);
    }
}

// ---------------- bf16 MFMA GEMM ----------------
// C[M,N] = A[M,K] @ Bt[N,K]^T (+bias). A,Bt bf16 K-major; acc fp32.
// 128x128 block tile, 256 threads = 4 waves in 2x2, each wave 64x64 via 4x4 of 16x16x32 MFMA.
// LDS tiles stored as 16B chunks: chunk(row,kg) at index row*4 + (kg ^ ((row>>1)&3)).

template<bool STORE_BF16>
__global__ __launch_bounds__(256) void gemm_mfma(const __hip_bfloat16* __restrict__ A,
                                                 const __hip_bfloat16* __restrict__ Bt,
                                                 const float* __restrict__ bias,
                                                 float* __restrict__ Cf,
                                                 __hip_bfloat16* __restrict__ Cb,
                                                 int M, int N, int K) {
    __shared__ short As[4096];   // 128 rows x 32 k (bf16), swizzled 16B chunks
    __shared__ short Bs[4096];
    int t = threadIdx.x;
    int lane = t & 63;
    int w = t >> 6;
    int m0 = blockIdx.x * 128;
    int n0 = blockIdx.y * 128;
    int wm = (w >> 1) * 64, wn = (w & 1) * 64;

    // staging: thread t handles chunks c0=t, c1=t+256 of each tile (512 chunks = 8KB)
    int c0 = t, c1 = t + 256;
    int row0 = c0 >> 2, row1 = c1 >> 2;
    int kg0 = (c0 & 3) ^ ((row0 >> 1) & 3);
    int kg1 = (c1 & 3) ^ ((row1 >> 1) & 3);
    int am0 = m0 + row0; if (am0 > M - 1) am0 = M - 1;
    int am1 = m0 + row1; if (am1 > M - 1) am1 = M - 1;
    const __hip_bfloat16* Ag0 = A + (size_t)am0 * K + kg0 * 8;
    const __hip_bfloat16* Ag1 = A + (size_t)am1 * K + kg1 * 8;
    const __hip_bfloat16* Bg0 = Bt + (size_t)(n0 + row0) * K + kg0 * 8;
    const __hip_bfloat16* Bg1 = Bt + (size_t)(n0 + row1) * K + kg1 * 8;
    short* lA0 = &As[(t & 192) * 8];            // wave-uniform LDS base, HW adds lane*16
    short* lA1 = &As[(256 + (t & 192)) * 8];
    short* lB0 = &Bs[(t & 192) * 8];
    short* lB1 = &Bs[(256 + (t & 192)) * 8];

    floatx4 acc[4][4];
#pragma unroll
    for (int i = 0; i < 4; i++)
#pragma unroll
        for (int j = 0; j < 4; j++) acc[i][j] = (floatx4){0.f, 0.f, 0.f, 0.f};

    int quad = lane >> 4;
    int lm = lane & 15;

    for (int k0 = 0; k0 < K; k0 += 32) {
        ASYNC16(Ag0 + k0, lA0);
        ASYNC16(Ag1 + k0, lA1);
        ASYNC16(Bg0 + k0, lB0);
        ASYNC16(Bg1 + k0, lB1);
        __syncthreads();   // drains vmcnt, LDS tiles ready

        short8 af[4], bf[4];
#pragma unroll
        for (int i = 0; i < 4; i++) {
            int rm = wm + i * 16 + lm;
            af[i] = *(const short8*)&As[(rm * 4 + (quad ^ ((rm >> 1) & 3))) * 8];
            int rn = wn + i * 16 + lm;
            bf[i] = *(const short8*)&Bs[(rn * 4 + (quad ^ ((rn >> 1) & 3))) * 8];
        }
#pragma unroll
        for (int i = 0; i < 4; i++)
#pragma unroll
            for (int j = 0; j < 4; j++)
                acc[i][j] = __builtin_amdgcn_mfma_f32_16x16x32_bf16(af[i], bf[j], acc[i][j], 0, 0, 0);
        __syncthreads();   // all reads done before next staging overwrites
    }

    // C/D layout: col = lane&15, row = (lane>>4)*4 + reg
    int lr = (lane >> 4) * 4;
#pragma unroll
    for (int i = 0; i < 4; i++) {
#pragma unroll
        for (int j = 0; j < 4; j++) {
            int col = n0 + wn + j * 16 + lm;
            float bv = bias ? bias[col] : 0.0f;
#pragma unroll
            for (int r = 0; r < 4; r++) {
                int row = m0 + wm + i * 16 + lr + r;
                if (row < M) {
                    float v = acc[i][j][r] + bv;
                    if (STORE_BF16) Cb[(size_t)row * N + col] = __float2bfloat16(v);
                    else            Cf[(size_t)row * N + col] = v;
                }
            }
        }
    }
}

// ---------------- el/er for all 3 etypes ----------------

__global__ __launch_bounds__(256) void elr3_kernel(const __hip_bfloat16* __restrict__ f,
                                                   const float* __restrict__ al0, const float* __restrict__ al1,
                                                   const float* __restrict__ al2, const float* __restrict__ ar0,
                                                   const float* __restrict__ ar1, const float* __restrict__ ar2,
                                                   float* __restrict__ el, float* __restrict__ er) {
    int n = blockIdx.x;
    int h = threadIdx.x >> 6;
    int d = threadIdx.x & 63;
#pragma unroll
    for (int t = 0; t < 3; t++) {
        const float* al = t == 0 ? al0 : (t == 1 ? al1 : al2);
        const float* ar = t == 0 ? ar0 : (t == 1 ? ar1 : ar2);
        float v = __bfloat162float(f[(size_t)n * 768 + t * 256 + h * DD + d]);
        float vl = v * al[h * DD + d];
        float vr = v * ar[h * DD + d];
#pragma unroll
        for (int off = 32; off; off >>= 1) {
            vl += __shfl_down(vl, off);
            vr += __shfl_down(vr, off);
        }
        if (d == 0) {
            el[(n * 3 + t) * HH + h] = vl;
            er[(n * 3 + t) * HH + h] = vr;
        }
    }
}

// ---------------- per-dst online-softmax aggregation over CSR ----------------
// f points at f_all + t*256 (row stride 768); el/er point at el_all + t*4 (stride 12).

__global__ __launch_bounds__(256) void aggregate_kernel(const int* __restrict__ rowptr,
                                                        const int* __restrict__ colsrc,
                                                        const __hip_bfloat16* __restrict__ f,
                                                        const float* __restrict__ el,
                                                        const float* __restrict__ er,
                                                        const float* __restrict__ bias,
                                                        float* __restrict__ out, int accumulate) {
    int n = blockIdx.x;
    int h = threadIdx.x >> 6;
    int d = threadIdx.x & 63;
    int beg = rowptr[n], end = rowptr[n + 1];
    float ern = er[n * 12 + h];
    float m = -INFINITY, s = 0.f, acc = 0.f;
    for (int p = beg; p < end; p++) {
        int srcn = colsrc[p];
        float e = el[srcn * 12 + h] + ern;
        e = (e > 0.f) ? e : 0.2f * e;           // leaky_relu slope 0.2
        float mn = fmaxf(m, e);
        float scale = __expf(m - mn);
        float wgt = __expf(e - mn);
        s = s * scale + wgt;
        acc = acc * scale + wgt * __bfloat162float(f[(size_t)srcn * 768 + h * DD + d]);
        m = mn;
    }
    float res = (s > 0.f) ? acc / s : 0.f;
    res += bias[h * DD + d];
    size_t oi = (size_t)n * HDIM + h * DD + d;
    if (accumulate) out[oi] += res;
    else out[oi] = res;
}

// ---------------- launch ----------------

extern "C" void kernel_launch(void* const* d_in, const int* in_sizes, int n_in,
                              void* d_out, int out_size, void* d_ws, size_t ws_size,
                              hipStream_t stream) {
    const float* x = (const float*)d_in[0];
    const int* src[3] = {(const int*)d_in[1], (const int*)d_in[3], (const int*)d_in[5]};
    const int* dst[3] = {(const int*)d_in[2], (const int*)d_in[4], (const int*)d_in[6]};
    const float *W[2][3], *AL[2][3], *AR[2][3], *BB[2][3];
    int idx = 7;
    for (int l = 0; l < 2; l++)
        for (int t = 0; t < 3; t++) {
            W[l][t]  = (const float*)d_in[idx++];
            AL[l][t] = (const float*)d_in[idx++];
            AR[l][t] = (const float*)d_in[idx++];
            BB[l][t] = (const float*)d_in[idx++];
        }
    const float* Wout = (const float*)d_in[31];
    const float* bout = (const float*)d_in[32];
    float* out = (float*)d_out;

    // ---- workspace carve (~154 MB) ----
    char* p = (char*)d_ws;
    __hip_bfloat16* f_all = (__hip_bfloat16*)p; p += (size_t)NN * 768 * 2;   // 61.44 MB
    char* regionA = p;                          p += (size_t)NN * 1024 * 2;  // 81.92 MB (xb | hbuf+hb)
    float* el_all = (float*)p;                  p += (size_t)NN * 12 * 4;
    float* er_all = (float*)p;                  p += (size_t)NN * 12 * 4;
    __hip_bfloat16* Wt0 = (__hip_bfloat16*)p;   p += (size_t)768 * 1024 * 2;
    __hip_bfloat16* Wt1 = (__hip_bfloat16*)p;   p += (size_t)768 * 256 * 2;
    __hip_bfloat16* Wto = (__hip_bfloat16*)p;   p += (size_t)1024 * 256 * 2;
    int* ibase = (int*)p;
    int *rowptr[3], *colsrc[3], *cursor[3];
    for (int t = 0; t < 3; t++) {
        rowptr[t] = ibase; ibase += NN + 1;
        colsrc[t] = ibase; ibase += EE;
        cursor[t] = ibase; ibase += NN;
    }
    // regionA lifetimes: xb (GEMM0 input) dead before hbuf/hb written
    __hip_bfloat16* xb = (__hip_bfloat16*)regionA;
    float* hbuf = (float*)regionA;
    __hip_bfloat16* hb = (__hip_bfloat16*)(regionA + (size_t)NN * HDIM * 4);

    // ---- CSR build ----
    for (int t = 0; t < 3; t++) {
        zero_kernel<<<(NN + 255) / 256, 256, 0, stream>>>(cursor[t], NN);
        count_kernel<<<(EE + 255) / 256, 256, 0, stream>>>(dst[t], cursor[t], EE);
    }
    scan3_kernel<<<3, 1024, 0, stream>>>(cursor[0], cursor[1], cursor[2],
                                         rowptr[0], rowptr[1], rowptr[2], NN);
    for (int t = 0; t < 3; t++) {
        zero_kernel<<<(NN + 255) / 256, 256, 0, stream>>>(cursor[t], NN);
        scatter_kernel<<<(EE + 255) / 256, 256, 0, stream>>>(src[t], dst[t], rowptr[t],
                                                             cursor[t], colsrc[t], EE);
    }

    // ---- pack inputs/weights to bf16 ----
    f2b_kernel<<<(NN * 1024 + 255) / 256, 256, 0, stream>>>(x, xb, NN * 1024);
    for (int t = 0; t < 3; t++) {
        transb_kernel<<<(1024 * 256 + 255) / 256, 256, 0, stream>>>(W[0][t], Wt0 + (size_t)t * 256 * 1024, 1024, 256);
        transb_kernel<<<(256 * 256 + 255) / 256, 256, 0, stream>>>(W[1][t], Wt1 + (size_t)t * 256 * 256, 256, 256);
    }
    transb_kernel<<<(256 * 1024 + 255) / 256, 256, 0, stream>>>(Wout, Wto, 256, 1024);

    // ---- layer 0 ----
    gemm_mfma<true><<<dim3(313, 6), 256, 0, stream>>>(xb, Wt0, nullptr, nullptr, f_all, NN, 768, 1024);
    elr3_kernel<<<NN, 256, 0, stream>>>(f_all, AL[0][0], AL[0][1], AL[0][2],
                                        AR[0][0], AR[0][1], AR[0][2], el_all, er_all);
    for (int t = 0; t < 3; t++)
        aggregate_kernel<<<NN, 256, 0, stream>>>(rowptr[t], colsrc[t], f_all + t * 256,
                                                 el_all + t * 4, er_all + t * 4,
                                                 BB[0][t], hbuf, t > 0);
    leakyb_kernel<<<(NN * HDIM + 255) / 256, 256, 0, stream>>>(hbuf, hb, 0.01f, NN * HDIM);

    // ---- layer 1 ----
    gemm_mfma<true><<<dim3(313, 6), 256, 0, stream>>>(hb, Wt1, nullptr, nullptr, f_all, NN, 768, 256);
    elr3_kernel<<<NN, 256, 0, stream>>>(f_all, AL[1][0], AL[1][1], AL[1][2],
                                        AR[1][0], AR[1][1], AR[1][2], el_all, er_all);
    for (int t = 0; t < 3; t++)
        aggregate_kernel<<<NN, 256, 0, stream>>>(rowptr[t], colsrc[t], f_all + t * 256,
                                                 el_all + t * 4, er_all + t * 4,
                                                 BB[1][t], hbuf, t > 0);
    leakyb_kernel<<<(NN * HDIM + 255) / 256, 256, 0, stream>>>(hbuf, hb, 1.0f, NN * HDIM);

    // ---- output projection ----
    gemm_mfma<false><<<dim3(313, 8), 256, 0, stream>>>(hb, Wto, bout, out, nullptr, NN, 1024, 256);
}

// Round 3
// 1198.606 us; speedup vs baseline: 2.2073x; 1.1666x over previous
//
#include <hip/hip_runtime.h>
#include <hip/hip_bf16.h>
#include <math.h>

#define NN 40000
#define EE 250000
#define HH 4
#define DD 64
#define HDIM 256

typedef __attribute__((ext_vector_type(8))) short short8;
typedef __attribute__((ext_vector_type(4))) float floatx4;

#define ASYNC16(G, L) __builtin_amdgcn_global_load_lds( \
    (const __attribute__((address_space(1))) void*)(G), \
    (__attribute__((address_space(3))) void*)(L), 16, 0, 0)

// ---------------- CSR build ----------------

__global__ void zero_kernel(int* p, int n) {
    int i = blockIdx.x * blockDim.x + threadIdx.x;
    if (i < n) p[i] = 0;
}

// grid.y = etype
__global__ void count3_kernel(const int* __restrict__ d0, const int* __restrict__ d1,
                              const int* __restrict__ d2, int* __restrict__ deg_all, int n) {
    int i = blockIdx.x * blockDim.x + threadIdx.x;
    int t = blockIdx.y;
    const int* dst = t == 0 ? d0 : (t == 1 ? d1 : d2);
    if (i < n) atomicAdd(&deg_all[t * NN + dst[i]], 1);
}

__global__ __launch_bounds__(1024) void scan3_kernel(const int* __restrict__ deg_all,
                                                     int* __restrict__ rowptr_all, int n) {
    const int* deg = deg_all + blockIdx.x * NN;
    int* rowptr = rowptr_all + blockIdx.x * (NN + 1);
    __shared__ int buf[1024];
    __shared__ int carry_s;
    int tid = threadIdx.x;
    if (tid == 0) { carry_s = 0; rowptr[0] = 0; }
    __syncthreads();
    for (int base = 0; base < n; base += 1024) {
        int i = base + tid;
        int v = (i < n) ? deg[i] : 0;
        buf[tid] = v;
        __syncthreads();
        for (int off = 1; off < 1024; off <<= 1) {
            int t = (tid >= off) ? buf[tid - off] : 0;
            __syncthreads();
            buf[tid] += t;
            __syncthreads();
        }
        int incl = buf[tid];
        int tot = buf[1023];
        if (i < n) rowptr[i + 1] = carry_s + incl;
        __syncthreads();
        if (tid == 0) carry_s += tot;
        __syncthreads();
    }
}

__global__ void scatter3_kernel(const int* __restrict__ s0, const int* __restrict__ s1,
                                const int* __restrict__ s2, const int* __restrict__ d0,
                                const int* __restrict__ d1, const int* __restrict__ d2,
                                const int* __restrict__ rowptr_all, int* __restrict__ cur_all,
                                int* __restrict__ colsrc_all, int n) {
    int i = blockIdx.x * blockDim.x + threadIdx.x;
    int t = blockIdx.y;
    const int* src = t == 0 ? s0 : (t == 1 ? s1 : s2);
    const int* dst = t == 0 ? d0 : (t == 1 ? d1 : d2);
    if (i < n) {
        int d = dst[i];
        int p = rowptr_all[t * (NN + 1) + d] + atomicAdd(&cur_all[t * NN + d], 1);
        colsrc_all[t * EE + p] = src[i];
    }
}

// ---------------- conversions / weight packing ----------------

__global__ void f2b_kernel(const float* __restrict__ in, __hip_bfloat16* __restrict__ o, int n) {
    int i = blockIdx.x * blockDim.x + threadIdx.x;
    if (i < n) o[i] = __float2bfloat16(in[i]);
}

// Wt[n][k] = bf16(W[k][n]);  W is K x Nc row-major.
__global__ void transb_kernel(const float* __restrict__ W, __hip_bfloat16* __restrict__ Wt,
                              int K, int Nc) {
    int i = blockIdx.x * blockDim.x + threadIdx.x;
    if (i < K * Nc) {
        int k = i / Nc, n2 = i % Nc;
        Wt[(size_t)n2 * K + k] = __float2bfloat16(W[i]);
    }
}

// ---------------- bf16 MFMA GEMM ----------------
// C[M,N] = A[M,K] @ Bt[N,K]^T (+bias). Grid: x = n-tile (fastest, shares A panel), y = m-tile.

template<bool STORE_BF16>
__global__ __launch_bounds__(256) void gemm_mfma(const __hip_bfloat16* __restrict__ A,
                                                 const __hip_bfloat16* __restrict__ Bt,
                                                 const float* __restrict__ bias,
                                                 float* __restrict__ Cf,
                                                 __hip_bfloat16* __restrict__ Cb,
                                                 int M, int N, int K) {
    __shared__ short As[4096];   // 128 rows x 32 k (bf16), swizzled 16B chunks
    __shared__ short Bs[4096];
    int t = threadIdx.x;
    int lane = t & 63;
    int w = t >> 6;
    int m0 = blockIdx.y * 128;
    int n0 = blockIdx.x * 128;
    int wm = (w >> 1) * 64, wn = (w & 1) * 64;

    int c0 = t, c1 = t + 256;
    int row0 = c0 >> 2, row1 = c1 >> 2;
    int kg0 = (c0 & 3) ^ ((row0 >> 1) & 3);
    int kg1 = (c1 & 3) ^ ((row1 >> 1) & 3);
    int am0 = m0 + row0; if (am0 > M - 1) am0 = M - 1;
    int am1 = m0 + row1; if (am1 > M - 1) am1 = M - 1;
    const __hip_bfloat16* Ag0 = A + (size_t)am0 * K + kg0 * 8;
    const __hip_bfloat16* Ag1 = A + (size_t)am1 * K + kg1 * 8;
    const __hip_bfloat16* Bg0 = Bt + (size_t)(n0 + row0) * K + kg0 * 8;
    const __hip_bfloat16* Bg1 = Bt + (size_t)(n0 + row1) * K + kg1 * 8;
    short* lA0 = &As[(t & 192) * 8];
    short* lA1 = &As[(256 + (t & 192)) * 8];
    short* lB0 = &Bs[(t & 192) * 8];
    short* lB1 = &Bs[(256 + (t & 192)) * 8];

    floatx4 acc[4][4];
#pragma unroll
    for (int i = 0; i < 4; i++)
#pragma unroll
        for (int j = 0; j < 4; j++) acc[i][j] = (floatx4){0.f, 0.f, 0.f, 0.f};

    int quad = lane >> 4;
    int lm = lane & 15;

    for (int k0 = 0; k0 < K; k0 += 32) {
        ASYNC16(Ag0 + k0, lA0);
        ASYNC16(Ag1 + k0, lA1);
        ASYNC16(Bg0 + k0, lB0);
        ASYNC16(Bg1 + k0, lB1);
        __syncthreads();

        short8 af[4], bf[4];
#pragma unroll
        for (int i = 0; i < 4; i++) {
            int rm = wm + i * 16 + lm;
            af[i] = *(const short8*)&As[(rm * 4 + (quad ^ ((rm >> 1) & 3))) * 8];
            int rn = wn + i * 16 + lm;
            bf[i] = *(const short8*)&Bs[(rn * 4 + (quad ^ ((rn >> 1) & 3))) * 8];
        }
#pragma unroll
        for (int i = 0; i < 4; i++)
#pragma unroll
            for (int j = 0; j < 4; j++)
                acc[i][j] = __builtin_amdgcn_mfma_f32_16x16x32_bf16(af[i], bf[j], acc[i][j], 0, 0, 0);
        __syncthreads();
    }

    int lr = (lane >> 4) * 4;
#pragma unroll
    for (int i = 0; i < 4; i++) {
#pragma unroll
        for (int j = 0; j < 4; j++) {
            int col = n0 + wn + j * 16 + lm;
            float bv = bias ? bias[col] : 0.0f;
#pragma unroll
            for (int r = 0; r < 4; r++) {
                int row = m0 + wm + i * 16 + lr + r;
                if (row < M) {
                    float v = acc[i][j][r] + bv;
                    if (STORE_BF16) Cb[(size_t)row * N + col] = __float2bfloat16(v);
                    else            Cf[(size_t)row * N + col] = v;
                }
            }
        }
    }
}

// ---------------- el/er for all 3 etypes ----------------

__global__ __launch_bounds__(256) void elr3_kernel(const __hip_bfloat16* __restrict__ f,
                                                   const float* __restrict__ al0, const float* __restrict__ al1,
                                                   const float* __restrict__ al2, const float* __restrict__ ar0,
                                                   const float* __restrict__ ar1, const float* __restrict__ ar2,
                                                   float* __restrict__ el, float* __restrict__ er) {
    int n = blockIdx.x;
    int h = threadIdx.x >> 6;
    int d = threadIdx.x & 63;
#pragma unroll
    for (int t = 0; t < 3; t++) {
        const float* al = t == 0 ? al0 : (t == 1 ? al1 : al2);
        const float* ar = t == 0 ? ar0 : (t == 1 ? ar1 : ar2);
        float v = __bfloat162float(f[(size_t)n * 768 + t * 256 + h * DD + d]);
        float vl = v * al[h * DD + d];
        float vr = v * ar[h * DD + d];
#pragma unroll
        for (int off = 32; off; off >>= 1) {
            vl += __shfl_down(vl, off);
            vr += __shfl_down(vr, off);
        }
        if (d == 0) {
            el[n * 12 + t * 4 + h] = vl;
            er[n * 12 + t * 4 + h] = vr;
        }
    }
}

// ---------------- fused 3-etype online-softmax aggregation + leaky + bf16 store ----------------
// Block = dst node; wave = head; lane = edge slot (phase 1) / channel (phase 2).

__global__ __launch_bounds__(256) void aggregate3_kernel(const int* __restrict__ rowptr_all,
                                                         const int* __restrict__ colsrc_all,
                                                         const __hip_bfloat16* __restrict__ f,
                                                         const float* __restrict__ el,
                                                         const float* __restrict__ er,
                                                         const float* __restrict__ b0,
                                                         const float* __restrict__ b1,
                                                         const float* __restrict__ b2,
                                                         float slope,
                                                         __hip_bfloat16* __restrict__ outb) {
    int n = blockIdx.x;
    int h = threadIdx.x >> 6;
    int d = threadIdx.x & 63;
    float total = 0.f;
#pragma unroll
    for (int t = 0; t < 3; t++) {
        const int* rowptr = rowptr_all + t * (NN + 1);
        const int* colsrc = colsrc_all + t * EE;
        const float* bias = t == 0 ? b0 : (t == 1 ? b1 : b2);
        int beg = rowptr[n], end = rowptr[n + 1];
        float ern = er[n * 12 + t * 4 + h];
        float m = -INFINITY, s = 0.f, acc = 0.f;
        for (int base = beg; base < end; base += 64) {
            int p = base + d;
            bool valid = p < end;
            int srcn = valid ? colsrc[p] : 0;
            float e = -INFINITY;
            if (valid) {
                float ev = el[srcn * 12 + t * 4 + h] + ern;
                e = (ev > 0.f) ? ev : 0.2f * ev;
            }
            float cm = e;
#pragma unroll
            for (int off = 32; off; off >>= 1) cm = fmaxf(cm, __shfl_xor(cm, off));
            float mn = fmaxf(m, cm);               // finite: >=1 valid lane
            float wgt = valid ? __expf(e - mn) : 0.f;
            float cs = wgt;
#pragma unroll
            for (int off = 32; off; off >>= 1) cs += __shfl_xor(cs, off);
            float scale = (m == -INFINITY) ? 0.f : __expf(m - mn);
            s = s * scale + cs;
            acc = acc * scale;
            int cnt = end - base; if (cnt > 64) cnt = 64;
            const __hip_bfloat16* fb = f + t * 256 + h * DD + d;
            int j = 0;
            for (; j + 4 <= cnt; j += 4) {
                int   i0 = __shfl(srcn, j),     i1 = __shfl(srcn, j + 1);
                int   i2 = __shfl(srcn, j + 2), i3 = __shfl(srcn, j + 3);
                float w0 = __shfl(wgt, j),      w1 = __shfl(wgt, j + 1);
                float w2 = __shfl(wgt, j + 2),  w3 = __shfl(wgt, j + 3);
                float f0 = __bfloat162float(fb[(size_t)i0 * 768]);
                float f1 = __bfloat162float(fb[(size_t)i1 * 768]);
                float f2 = __bfloat162float(fb[(size_t)i2 * 768]);
                float f3 = __bfloat162float(fb[(size_t)i3 * 768]);
                acc = fmaf(w0, f0, acc);
                acc = fmaf(w1, f1, acc);
                acc = fmaf(w2, f2, acc);
                acc = fmaf(w3, f3, acc);
            }
            for (; j < cnt; j++) {
                int   ij = __shfl(srcn, j);
                float wj = __shfl(wgt, j);
                acc = fmaf(wj, __bfloat162float(fb[(size_t)ij * 768]), acc);
            }
            m = mn;
        }
        float res = (s > 0.f) ? acc / s : 0.f;
        total += res + bias[h * DD + d];
    }
    total = (total >= 0.f) ? total : slope * total;
    outb[(size_t)n * HDIM + h * DD + d] = __float2bfloat16(total);
}

// ---------------- launch ----------------

extern "C" void kernel_launch(void* const* d_in, const int* in_sizes, int n_in,
                              void* d_out, int out_size, void* d_ws, size_t ws_size,
                              hipStream_t stream) {
    const float* x = (const float*)d_in[0];
    const int* src[3] = {(const int*)d_in[1], (const int*)d_in[3], (const int*)d_in[5]};
    const int* dst[3] = {(const int*)d_in[2], (const int*)d_in[4], (const int*)d_in[6]};
    const float *W[2][3], *AL[2][3], *AR[2][3], *BB[2][3];
    int idx = 7;
    for (int l = 0; l < 2; l++)
        for (int t = 0; t < 3; t++) {
            W[l][t]  = (const float*)d_in[idx++];
            AL[l][t] = (const float*)d_in[idx++];
            AR[l][t] = (const float*)d_in[idx++];
            BB[l][t] = (const float*)d_in[idx++];
        }
    const float* Wout = (const float*)d_in[31];
    const float* bout = (const float*)d_in[32];
    float* out = (float*)d_out;

    // ---- workspace carve ----
    char* p = (char*)d_ws;
    __hip_bfloat16* f_all = (__hip_bfloat16*)p; p += (size_t)NN * 768 * 2;   // 61.44 MB
    char* regionA = p;                          p += (size_t)NN * 1024 * 2;  // 81.92 MB (xb, then hb)
    float* el_all = (float*)p;                  p += (size_t)NN * 12 * 4;
    float* er_all = (float*)p;                  p += (size_t)NN * 12 * 4;
    __hip_bfloat16* Wt0 = (__hip_bfloat16*)p;   p += (size_t)768 * 1024 * 2;
    __hip_bfloat16* Wt1 = (__hip_bfloat16*)p;   p += (size_t)768 * 256 * 2;
    __hip_bfloat16* Wto = (__hip_bfloat16*)p;   p += (size_t)1024 * 256 * 2;
    int* rowptr_all = (int*)p;                  p += (size_t)3 * (NN + 1) * 4;
    int* colsrc_all = (int*)p;                  p += (size_t)3 * EE * 4;
    int* cursor_all = (int*)p;                  p += (size_t)3 * NN * 4;
    // regionA lifetimes: xb (layer-0 GEMM input) dead before hb written
    __hip_bfloat16* xb = (__hip_bfloat16*)regionA;
    __hip_bfloat16* hb = (__hip_bfloat16*)regionA;

    // ---- CSR build ----
    zero_kernel<<<(3 * NN + 255) / 256, 256, 0, stream>>>(cursor_all, 3 * NN);
    count3_kernel<<<dim3((EE + 255) / 256, 3), 256, 0, stream>>>(dst[0], dst[1], dst[2], cursor_all, EE);
    scan3_kernel<<<3, 1024, 0, stream>>>(cursor_all, rowptr_all, NN);
    zero_kernel<<<(3 * NN + 255) / 256, 256, 0, stream>>>(cursor_all, 3 * NN);
    scatter3_kernel<<<dim3((EE + 255) / 256, 3), 256, 0, stream>>>(src[0], src[1], src[2],
                                                                   dst[0], dst[1], dst[2],
                                                                   rowptr_all, cursor_all, colsrc_all, EE);

    // ---- pack inputs/weights to bf16 ----
    f2b_kernel<<<(NN * 1024 + 255) / 256, 256, 0, stream>>>(x, xb, NN * 1024);
    for (int t = 0; t < 3; t++) {
        transb_kernel<<<(1024 * 256 + 255) / 256, 256, 0, stream>>>(W[0][t], Wt0 + (size_t)t * 256 * 1024, 1024, 256);
        transb_kernel<<<(256 * 256 + 255) / 256, 256, 0, stream>>>(W[1][t], Wt1 + (size_t)t * 256 * 256, 256, 256);
    }
    transb_kernel<<<(256 * 1024 + 255) / 256, 256, 0, stream>>>(Wout, Wto, 256, 1024);

    // ---- layer 0 ----
    gemm_mfma<true><<<dim3(6, 313), 256, 0, stream>>>(xb, Wt0, nullptr, nullptr, f_all, NN, 768, 1024);
    elr3_kernel<<<NN, 256, 0, stream>>>(f_all, AL[0][0], AL[0][1], AL[0][2],
                                        AR[0][0], AR[0][1], AR[0][2], el_all, er_all);
    aggregate3_kernel<<<NN, 256, 0, stream>>>(rowptr_all, colsrc_all, f_all, el_all, er_all,
                                              BB[0][0], BB[0][1], BB[0][2], 0.01f, hb);

    // ---- layer 1 ----
    gemm_mfma<true><<<dim3(6, 313), 256, 0, stream>>>(hb, Wt1, nullptr, nullptr, f_all, NN, 768, 256);
    elr3_kernel<<<NN, 256, 0, stream>>>(f_all, AL[1][0], AL[1][1], AL[1][2],
                                        AR[1][0], AR[1][1], AR[1][2], el_all, er_all);
    aggregate3_kernel<<<NN, 256, 0, stream>>>(rowptr_all, colsrc_all, f_all, el_all, er_all,
                                              BB[1][0], BB[1][1], BB[1][2], 1.0f, hb);

    // ---- output projection ----
    gemm_mfma<false><<<dim3(8, 313), 256, 0, stream>>>(hb, Wto, bout, out, nullptr, NN, 1024, 256);
}